// Round 7
// baseline (7586.021 us; speedup 1.0000x reference)
//
#include <hip/hip_runtime.h>
#include <hip/hip_bf16.h>

#define L_SEQ 3136
#define BATCH 2
#define BLTOK 6272           // BATCH * L_SEQ
#define DM 384
#define DI 768
#define NS 16
#define DR 24
#define NCH 112              // chunks per (b,dir) scan
#define CHL 28               // steps per chunk (112*28 = 3136)

typedef __attribute__((ext_vector_type(8))) short short8b;   // 8 x bf16
typedef __attribute__((ext_vector_type(4))) float f32x4;

__device__ __forceinline__ float silu_f(float x) { return x / (1.f + __expf(-x)); }

__device__ __forceinline__ unsigned short f2bf(float f) {
  union { float f; unsigned int u; } v; v.f = f;
  unsigned int r = v.u + 0x7fffu + ((v.u >> 16) & 1u);   // RNE
  return (unsigned short)(r >> 16);
}
__device__ __forceinline__ uint2 pack4(float4 v) {
  return make_uint2((unsigned)f2bf(v.x) | ((unsigned)f2bf(v.y) << 16),
                    (unsigned)f2bf(v.z) | ((unsigned)f2bf(v.w) << 16));
}

// ---------------- patch embed: im2col ----------------
__global__ void im2col_k(const float* __restrict__ x, float* __restrict__ xcol) {
  size_t i = (size_t)blockIdx.x * 256 + threadIdx.x;
  if (i >= (size_t)BLTOK * 768) return;
  int k = (int)(i % 768);
  size_t m = i / 768;
  int b = (int)(m / L_SEQ);
  int t = (int)((m / 196) % 16);
  int hw = (int)(m % 196);
  int hh = hw / 14, ww = hw % 14;
  int c = k >> 8, p = (k >> 4) & 15, q = k & 15;
  xcol[i] = x[((((size_t)b * 3 + c) * 16 + t) * 224 + hh * 16 + p) * 224 + ww * 16 + q];
}

// ---------------- patch embed epilogue ----------------
__global__ void epi_k(float* __restrict__ hid, const float* __restrict__ pb,
                      const float* __restrict__ pos, const float* __restrict__ tp,
                      float* __restrict__ res) {
  int m = blockIdx.x, d = threadIdx.x;
  int t = (m / 196) % 16;
  int hw = m % 196;
  size_t i = (size_t)m * DM + d;
  hid[i] += pb[d] + pos[(size_t)hw * DM + d] + tp[(size_t)t * DM + d];
  res[i] = 0.f;
}

// ---------------- residual add + RMSNorm ----------------
__global__ void rmsres_k(float* __restrict__ res, const float* __restrict__ hid,
                         const float* __restrict__ w, float* __restrict__ hn) {
  int r = blockIdx.x, d = threadIdx.x;
  size_t i = (size_t)r * DM + d;
  float s = res[i] + hid[i];
  res[i] = s;
  float sq = s * s;
  #pragma unroll
  for (int o = 1; o < 64; o <<= 1) sq += __shfl_xor(sq, o);
  __shared__ float part[8];
  __shared__ float scale;
  if ((d & 63) == 0) part[d >> 6] = sq;
  __syncthreads();
  if (d == 0) {
    float v = part[0] + part[1] + part[2] + part[3] + part[4] + part[5];
    scale = rsqrtf(v / (float)DM + 1e-5f);
  }
  __syncthreads();
  hn[i] = s * scale * w[d];
}

__global__ void final_k(const float* __restrict__ hid, const float* __restrict__ res,
                        const float* __restrict__ w, float* __restrict__ out) {
  int r = blockIdx.x, d = threadIdx.x;
  size_t i = (size_t)r * DM + d;
  float s = res[i] + hid[i];
  float sq = s * s;
  #pragma unroll
  for (int o = 1; o < 64; o <<= 1) sq += __shfl_xor(sq, o);
  __shared__ float part[8];
  __shared__ float scale;
  if ((d & 63) == 0) part[d >> 6] = sq;
  __syncthreads();
  if (d == 0) {
    float v = part[0] + part[1] + part[2] + part[3] + part[4] + part[5];
    scale = rsqrtf(v / (float)DM + 1e-5f);
  }
  __syncthreads();
  out[i] = s * scale * w[d];
}

// ---------------- bf16 MFMA GEMM: C[M,N] = (A [+A2]) * W^T ----------------
// Tile 128x128, BK=32, 4 waves (2x2), each wave 64x64 via 4x4 mfma_f32_16x16x32_bf16.
// LDS pre-packed in fragment order; frag read = ds_read_b128 at lane*16 (conflict-free).
template <bool ADD2>
__global__ __launch_bounds__(256) void gemm_bf16_k(const float* __restrict__ A, int lda,
                                                   const float* __restrict__ A2, int lda2,
                                                   const float* __restrict__ W,
                                                   float* __restrict__ C, int N, int K) {
  __shared__ __align__(16) uint2 As_l[1024];   // 8 KiB
  __shared__ __align__(16) uint2 Bs_l[1024];   // 8 KiB
  const int tid = threadIdx.x;
  const int m0 = blockIdx.y * 128, n0 = blockIdx.x * 128;
  const int lane = tid & 63, wv = tid >> 6;
  const int wr = wv >> 1, wc = wv & 1;
  f32x4 acc[4][4];
  #pragma unroll
  for (int i = 0; i < 4; ++i)
    #pragma unroll
    for (int j = 0; j < 4; ++j) acc[i][j] = (f32x4)0.f;

  for (int kt = 0; kt < K; kt += 32) {
    __syncthreads();
    #pragma unroll
    for (int i = 0; i < 4; ++i) {
      int q = tid + i * 256;
      int half = q & 1, l16 = (q >> 1) & 15, kg = (q >> 5) & 3, mb = q >> 7;
      int row = mb * 16 + l16, col = kg * 8 + half * 4;
      float4 va = *(const float4*)(A + (size_t)(m0 + row) * lda + kt + col);
      if (ADD2) {
        float4 v2 = *(const float4*)(A2 + (size_t)(m0 + row) * lda2 + kt + col);
        va.x += v2.x; va.y += v2.y; va.z += v2.z; va.w += v2.w;
      }
      As_l[q] = pack4(va);
      float4 vw = *(const float4*)(W + (size_t)(n0 + row) * K + kt + col);
      Bs_l[q] = pack4(vw);
    }
    __syncthreads();
    short8b a[4], b[4];
    #pragma unroll
    for (int i = 0; i < 4; ++i) a[i] = ((const short8b*)As_l)[(wr * 4 + i) * 64 + lane];
    #pragma unroll
    for (int j = 0; j < 4; ++j) b[j] = ((const short8b*)Bs_l)[(wc * 4 + j) * 64 + lane];
    #pragma unroll
    for (int i = 0; i < 4; ++i)
      #pragma unroll
      for (int j = 0; j < 4; ++j)
        acc[i][j] = __builtin_amdgcn_mfma_f32_16x16x32_bf16(a[i], b[j], acc[i][j], 0, 0, 0);
  }

  const int r4 = (lane >> 4) * 4, cc = lane & 15;
  #pragma unroll
  for (int i = 0; i < 4; ++i) {
    #pragma unroll
    for (int v = 0; v < 4; ++v) {
      int row = m0 + wr * 64 + i * 16 + r4 + v;
      float* cp = C + (size_t)row * N + n0 + wc * 64 + cc;
      #pragma unroll
      for (int j = 0; j < 4; ++j) cp[j * 16] = acc[i][j][v];
    }
  }
}

// ---------------- causal conv (both directions) + SiLU ----------------
__global__ void conv_k(const float* __restrict__ xz,
                       const float* __restrict__ cw, const float* __restrict__ cb,
                       const float* __restrict__ cwb, const float* __restrict__ cbb,
                       float* __restrict__ xcf, float* __restrict__ xcb) {
  int r = blockIdx.x, dir = blockIdx.y;
  int b = r / L_SEQ, t = r % L_SEQ;
  const float* cwp = dir ? cwb : cw;
  const float* cbp = dir ? cbb : cb;
  float* outp = dir ? xcb : xcf;
  for (int d = threadIdx.x; d < DI; d += blockDim.x) {
    float acc = cbp[d];
    #pragma unroll
    for (int k = 0; k < 4; ++k) {
      int s = t - 3 + k;
      if (s >= 0) {
        int si = dir ? (L_SEQ - 1 - s) : s;
        acc += xz[((size_t)b * L_SEQ + si) * (2 * DI) + d] * cwp[d * 4 + k];
      }
    }
    outp[((size_t)b * L_SEQ + t) * DI + d] = silu_f(acc);
  }
}

// ---------------- xproj stage 1 (MFMA): dbl = xc @ xw^T  [M=6272, N=56->64, K=768] ----------------
__global__ __launch_bounds__(256) void xproj1m_k(
    const float* __restrict__ xcf, const float* __restrict__ xcb,
    const float* __restrict__ xw, const float* __restrict__ xwb,
    float* __restrict__ dblR, float* __restrict__ BCf, float* __restrict__ BCb) {
  __shared__ __align__(16) uint2 As_l[512];    // 4 KiB
  __shared__ __align__(16) uint2 Bs_l[512];    // 4 KiB
  const int tid = threadIdx.x;
  const int m0 = blockIdx.x * 64;
  const int dir = blockIdx.y;
  const float* A  = (dir ? xcb : xcf);
  const float* Wm = (dir ? xwb : xw);
  float* BCp = (dir ? BCb : BCf);
  const int lane = tid & 63, wv = tid >> 6;
  f32x4 acc[4];
  #pragma unroll
  for (int j = 0; j < 4; ++j) acc[j] = (f32x4)0.f;

  for (int kt = 0; kt < DI; kt += 32) {
    __syncthreads();
    #pragma unroll
    for (int i = 0; i < 2; ++i) {
      int q = tid + i * 256;
      int half = q & 1, l16 = (q >> 1) & 15, kg = (q >> 5) & 3, mb = q >> 7;
      int row = mb * 16 + l16, col = kg * 8 + half * 4;
      float4 va = *(const float4*)(A + (size_t)(m0 + row) * DI + kt + col);
      As_l[q] = pack4(va);
      float4 vw = make_float4(0.f, 0.f, 0.f, 0.f);
      if (row < 56) vw = *(const float4*)(Wm + (size_t)row * DI + kt + col);
      Bs_l[q] = pack4(vw);
    }
    __syncthreads();
    short8b a = ((const short8b*)As_l)[wv * 64 + lane];
    #pragma unroll
    for (int j = 0; j < 4; ++j) {
      short8b b = ((const short8b*)Bs_l)[j * 64 + lane];
      acc[j] = __builtin_amdgcn_mfma_f32_16x16x32_bf16(a, b, acc[j], 0, 0, 0);
    }
  }

  const int r4 = (lane >> 4) * 4, cc = lane & 15;
  #pragma unroll
  for (int j = 0; j < 4; ++j) {
    int col = j * 16 + cc;
    #pragma unroll
    for (int v = 0; v < 4; ++v) {
      int row = m0 + wv * 16 + r4 + v;
      float val = acc[j][v];
      if (col < 24)       dblR[((size_t)dir * BLTOK + row) * 32 + col] = val;
      else if (col < 56)  BCp[(size_t)row * 32 + (col - 24)] = val;
    }
  }
}

// ---------------- xproj stage 2: dt = softplus(dblR[:, :24] @ dw^T + db) ----------------
__global__ __launch_bounds__(256) void xproj2_k(
    const float* __restrict__ dblR,
    const float* __restrict__ dw, const float* __restrict__ dwb,
    const float* __restrict__ db, const float* __restrict__ dbb,
    float* __restrict__ dtf, float* __restrict__ dtb) {
  __shared__ float sd[32][24];
  const int r0 = blockIdx.x * 32;
  const int dir = blockIdx.y;
  const int tid = threadIdx.x;
  const float* dwp = (dir ? dwb : dw);
  const float* dbp = (dir ? dbb : db);
  float* dtp = (dir ? dtb : dtf);
  #pragma unroll
  for (int i = 0; i < 3; ++i) {
    int idx = tid + i * 256;
    int r = idx / 24, j = idx - r * 24;
    sd[r][j] = dblR[((size_t)dir * BLTOK + r0 + r) * 32 + j];
  }
  __syncthreads();
  #pragma unroll
  for (int kk = 0; kk < 3; ++kk) {
    int d = kk * 256 + tid;
    float w[24];
    #pragma unroll
    for (int j = 0; j < 24; j += 4) {
      float4 wv = *(const float4*)&dwp[(size_t)d * DR + j];
      w[j] = wv.x; w[j + 1] = wv.y; w[j + 2] = wv.z; w[j + 3] = wv.w;
    }
    float bias = dbp[d];
    for (int r = 0; r < 32; ++r) {
      float acc = bias;
      #pragma unroll
      for (int j = 0; j < 24; ++j) acc += sd[r][j] * w[j];
      float dt = acc > 20.f ? acc : __logf(1.f + __expf(acc));
      dtp[(size_t)(r0 + r) * DI + d] = dt;
    }
  }
}

// ---------------- scan pass A: per-chunk local state + decay product ----------------
// grid (NCH, 2, BATCH*3): 256-thread blocks, 3-way d-split for occupancy.
__global__ __launch_bounds__(256) void scanA_k(
    const float* __restrict__ dtf, const float* __restrict__ dtb,
    const float* __restrict__ xcf, const float* __restrict__ xcb,
    const float* __restrict__ BCf, const float* __restrict__ BCb,
    const float* __restrict__ Al, const float* __restrict__ Alb,
    float* __restrict__ Pbuf, float* __restrict__ Hloc) {
  int c = blockIdx.x, dir = blockIdx.y;
  int b = blockIdx.z / 3, ds = blockIdx.z % 3;
  int d = ds * 256 + threadIdx.x;
  const float* dtp = (dir ? dtb : dtf) + (size_t)b * L_SEQ * DI + d;
  const float* up  = (dir ? xcb : xcf) + (size_t)b * L_SEQ * DI + d;
  const float* bcp = (dir ? BCb : BCf) + (size_t)b * L_SEQ * 32;
  const float* alp = (dir ? Alb : Al) + (size_t)d * NS;
  float A[NS], h[NS], P[NS];
  #pragma unroll
  for (int n = 0; n < NS; ++n) { A[n] = -__expf(alp[n]); h[n] = 0.f; P[n] = 1.f; }
  int t0 = c * CHL;
  for (int t = t0; t < t0 + CHL; ++t) {
    float dt = dtp[(size_t)t * DI];
    float u  = up[(size_t)t * DI];
    float du = dt * u;
    const float* bc = bcp + (size_t)t * 32;
    #pragma unroll
    for (int n = 0; n < NS; ++n) {
      float a = __expf(dt * A[n]);
      h[n] = a * h[n] + du * bc[n];
      P[n] *= a;
    }
  }
  size_t base = ((((size_t)b * 2 + dir) * NCH + c) * DI + d) * NS;
  #pragma unroll
  for (int n = 0; n < NS; n += 4) {
    *(float4*)&Pbuf[base + n] = make_float4(P[n], P[n + 1], P[n + 2], P[n + 3]);
    *(float4*)&Hloc[base + n] = make_float4(h[n], h[n + 1], h[n + 2], h[n + 3]);
  }
}

// ---------------- scan pass B (parallel): one thread per (d,n); serial over NCH chunks ----------------
// grid (48, 2, BATCH) x 256 threads = 49152 threads.
__global__ __launch_bounds__(256) void scanBp_k(float* __restrict__ Pbuf,
                                                const float* __restrict__ Hloc) {
  const int dir = blockIdx.y, b = blockIdx.z;
  const int flat = blockIdx.x * 256 + threadIdx.x;           // d*NS + n
  const size_t stride = (size_t)DI * NS;                     // chunk stride
  size_t base = (size_t)(b * 2 + dir) * NCH * DI * NS + flat;
  float h = 0.f;
  float Pc = Pbuf[base];
  float Hc = Hloc[base];
  for (int c = 0; c < NCH; ++c) {
    float P = Pc, H = Hc;
    size_t nxt = base + stride;
    if (c + 1 < NCH) {                 // prefetch next chunk while FMA runs
      Pc = Pbuf[nxt];
      Hc = Hloc[nxt];
    }
    Pbuf[base] = h;                    // store chunk-entry state
    h = P * h + H;
    base = nxt;
  }
}

// ---------------- scan pass C: replay with entry state, emit gated output ----------------
// grid (NCH, 2, BATCH*3): 256-thread blocks, 3-way d-split.
__global__ __launch_bounds__(256) void scanC_k(
    float* __restrict__ dtf, float* __restrict__ dtb,
    const float* __restrict__ xcf, const float* __restrict__ xcb,
    const float* __restrict__ BCf, const float* __restrict__ BCb,
    const float* __restrict__ Al, const float* __restrict__ Alb,
    const float* __restrict__ Dd, const float* __restrict__ Ddb,
    float* __restrict__ xz, const float* __restrict__ Hstart) {
  int c = blockIdx.x, dir = blockIdx.y;
  int b = blockIdx.z / 3, ds = blockIdx.z % 3;
  int d = ds * 256 + threadIdx.x;
  float* dtp = (dir ? dtb : dtf) + (size_t)b * L_SEQ * DI + d;
  const float* up  = (dir ? xcb : xcf) + (size_t)b * L_SEQ * DI + d;
  const float* bcp = (dir ? BCb : BCf) + (size_t)b * L_SEQ * 32;
  const float* alp = (dir ? Alb : Al) + (size_t)d * NS;
  float Ddv = (dir ? Ddb : Dd)[d];
  float A[NS], h[NS];
  size_t base = ((((size_t)b * 2 + dir) * NCH + c) * DI + d) * NS;
  #pragma unroll
  for (int n = 0; n < NS; ++n) A[n] = -__expf(alp[n]);
  #pragma unroll
  for (int n = 0; n < NS; n += 4) {
    float4 h4 = *(const float4*)&Hstart[base + n];
    h[n] = h4.x; h[n + 1] = h4.y; h[n + 2] = h4.z; h[n + 3] = h4.w;
  }
  int t0 = c * CHL;
  for (int t = t0; t < t0 + CHL; ++t) {
    float dt = dtp[(size_t)t * DI];
    float u  = up[(size_t)t * DI];
    float du = dt * u;
    const float* bc = bcp + (size_t)t * 32;
    float y = 0.f;
    #pragma unroll
    for (int n = 0; n < NS; ++n) {
      float a = __expf(dt * A[n]);
      h[n] = a * h[n] + du * bc[n];
      y += h[n] * bc[16 + n];
    }
    y += u * Ddv;
    if (dir == 0) {
      size_t row = (size_t)b * L_SEQ + t;
      float z = xz[row * (2 * DI) + DI + d];
      dtp[(size_t)t * DI] = y * silu_f(z);
    } else {
      int tr = L_SEQ - 1 - t;
      size_t row = (size_t)b * L_SEQ + tr;
      float z = xz[row * (2 * DI) + DI + d];
      xz[row * (2 * DI) + d] = y * silu_f(z);
    }
  }
}

extern "C" void kernel_launch(void* const* d_in, const int* in_sizes, int n_in,
                              void* d_out, int out_size, void* d_ws, size_t ws_size,
                              hipStream_t stream) {
  const float* x        = (const float*)d_in[0];
  // d_in[1] = sgn_lengths (unused)
  const float* patch_w  = (const float*)d_in[2];
  const float* patch_b  = (const float*)d_in[3];
  const float* pos_emb  = (const float*)d_in[4];
  const float* temp_pos = (const float*)d_in[5];
  const float* in_proj_w= (const float*)d_in[6];
  const float* conv_w   = (const float*)d_in[7];
  const float* conv_b   = (const float*)d_in[8];
  const float* conv_w_b = (const float*)d_in[9];
  const float* conv_b_b = (const float*)d_in[10];
  const float* xproj_w  = (const float*)d_in[11];
  const float* xproj_w_b= (const float*)d_in[12];
  const float* dt_w     = (const float*)d_in[13];
  const float* dt_bias  = (const float*)d_in[14];
  const float* dt_w_b   = (const float*)d_in[15];
  const float* dt_bias_b= (const float*)d_in[16];
  const float* A_log    = (const float*)d_in[17];
  const float* A_log_b  = (const float*)d_in[18];
  const float* Ds       = (const float*)d_in[19];
  const float* Ds_b     = (const float*)d_in[20];
  const float* out_pw   = (const float*)d_in[21];
  const float* norm_w   = (const float*)d_in[22];
  const float* norm_f   = (const float*)d_in[23];
  float* out = (float*)d_out;

  // workspace layout (floats); total ~192 MiB
  float* ws = (float*)d_ws;
  const size_t SZH = (size_t)BLTOK * DM;
  float* hid = ws;
  float* res = hid + SZH;
  float* hn  = res + SZH;
  float* xz  = hn + SZH;                       // BLTOK * 1536
  float* xcf = xz + (size_t)BLTOK * 2 * DI;
  float* xcb = xcf + (size_t)BLTOK * DI;
  float* dtf = xcb + (size_t)BLTOK * DI;
  float* dtb = dtf + (size_t)BLTOK * DI;
  float* BCf = dtb + (size_t)BLTOK * DI;       // BLTOK*32 : [B(16) | C(16)]
  float* BCb = BCf + (size_t)BLTOK * 32;
  float* Pbuf= BCb + (size_t)BLTOK * 32;       // 2*2*NCH*DI*NS
  float* Hlc = Pbuf + (size_t)2 * 2 * NCH * DI * NS;
  float* dblR= Hlc + (size_t)2 * 2 * NCH * DI * NS;  // [2][BLTOK][32]

  // ---- patch embedding ----
  im2col_k<<<18816, 256, 0, stream>>>(x, xz);  // xz reused as im2col buffer
  gemm_bf16_k<false><<<dim3(3, 49), 256, 0, stream>>>(xz, DI, nullptr, 0, patch_w, hid, DM, DI);
  epi_k<<<BLTOK, DM, 0, stream>>>(hid, patch_b, pos_emb, temp_pos, res);

  // ---- 24 mamba layers ----
  for (int l = 0; l < 24; ++l) {
    rmsres_k<<<BLTOK, DM, 0, stream>>>(res, hid, norm_w + (size_t)l * DM, hn);
    gemm_bf16_k<false><<<dim3(12, 49), 256, 0, stream>>>(hn, DM, nullptr, 0,
        in_proj_w + (size_t)l * 2 * DI * DM, xz, 2 * DI, DM);
    conv_k<<<dim3(BLTOK, 2), 256, 0, stream>>>(xz,
        conv_w + (size_t)l * DI * 4, conv_b + (size_t)l * DI,
        conv_w_b + (size_t)l * DI * 4, conv_b_b + (size_t)l * DI, xcf, xcb);
    xproj1m_k<<<dim3(98, 2), 256, 0, stream>>>(xcf, xcb,
        xproj_w + (size_t)l * 56 * DI, xproj_w_b + (size_t)l * 56 * DI,
        dblR, BCf, BCb);
    xproj2_k<<<dim3(196, 2), 256, 0, stream>>>(dblR,
        dt_w + (size_t)l * DI * DR, dt_w_b + (size_t)l * DI * DR,
        dt_bias + (size_t)l * DI, dt_bias_b + (size_t)l * DI,
        dtf, dtb);
    scanA_k<<<dim3(NCH, 2, BATCH * 3), 256, 0, stream>>>(dtf, dtb, xcf, xcb, BCf, BCb,
        A_log + (size_t)l * DI * NS, A_log_b + (size_t)l * DI * NS, Pbuf, Hlc);
    scanBp_k<<<dim3(48, 2, BATCH), 256, 0, stream>>>(Pbuf, Hlc);
    scanC_k<<<dim3(NCH, 2, BATCH * 3), 256, 0, stream>>>(dtf, dtb, xcf, xcb, BCf, BCb,
        A_log + (size_t)l * DI * NS, A_log_b + (size_t)l * DI * NS,
        Ds + (size_t)l * DI, Ds_b + (size_t)l * DI, xz, Pbuf);
    gemm_bf16_k<true><<<dim3(3, 49), 256, 0, stream>>>(dtf, DI, xz, 2 * DI,
        out_pw + (size_t)l * DM * DI, hid, DM, DI);
  }

  // ---- final norm ----
  final_k<<<BLTOK, DM, 0, stream>>>(hid, res, norm_f, out);
}

// Round 8
// 6947.367 us; speedup vs baseline: 1.0919x; 1.0919x over previous
//
#include <hip/hip_runtime.h>
#include <hip/hip_bf16.h>

#define L_SEQ 3136
#define BATCH 2
#define BLTOK 6272           // BATCH * L_SEQ
#define DM 384
#define DI 768
#define NS 16
#define DR 24
#define NCH 112              // chunks per (b,dir) scan
#define CHL 28               // steps per chunk (112*28 = 3136)

typedef __attribute__((ext_vector_type(8))) short short8b;   // 8 x bf16
typedef __attribute__((ext_vector_type(4))) float f32x4;
typedef unsigned short ushort_t;

__device__ __forceinline__ float silu_f(float x) { return x / (1.f + __expf(-x)); }

__device__ __forceinline__ unsigned short f2bf(float f) {
  union { float f; unsigned int u; } v; v.f = f;
  unsigned int r = v.u + 0x7fffu + ((v.u >> 16) & 1u);   // RNE
  return (unsigned short)(r >> 16);
}
__device__ __forceinline__ float bf2f(unsigned short s) {
  union { unsigned int u; float f; } v; v.u = (unsigned int)s << 16; return v.f;
}
__device__ __forceinline__ float lo16(unsigned int u) {
  union { unsigned int u; float f; } v; v.u = u << 16; return v.f;
}
__device__ __forceinline__ float hi16(unsigned int u) {
  union { unsigned int u; float f; } v; v.u = u & 0xffff0000u; return v.f;
}
__device__ __forceinline__ uint2 pack4(float4 v) {
  return make_uint2((unsigned)f2bf(v.x) | ((unsigned)f2bf(v.y) << 16),
                    (unsigned)f2bf(v.z) | ((unsigned)f2bf(v.w) << 16));
}

// ---------------- patch embed: im2col ----------------
__global__ void im2col_k(const float* __restrict__ x, float* __restrict__ xcol) {
  size_t i = (size_t)blockIdx.x * 256 + threadIdx.x;
  if (i >= (size_t)BLTOK * 768) return;
  int k = (int)(i % 768);
  size_t m = i / 768;
  int b = (int)(m / L_SEQ);
  int t = (int)((m / 196) % 16);
  int hw = (int)(m % 196);
  int hh = hw / 14, ww = hw % 14;
  int c = k >> 8, p = (k >> 4) & 15, q = k & 15;
  xcol[i] = x[((((size_t)b * 3 + c) * 16 + t) * 224 + hh * 16 + p) * 224 + ww * 16 + q];
}

// ---------------- patch embed epilogue ----------------
__global__ void epi_k(float* __restrict__ hid, const float* __restrict__ pb,
                      const float* __restrict__ pos, const float* __restrict__ tp,
                      float* __restrict__ res) {
  int m = blockIdx.x, d = threadIdx.x;
  int t = (m / 196) % 16;
  int hw = m % 196;
  size_t i = (size_t)m * DM + d;
  hid[i] += pb[d] + pos[(size_t)hw * DM + d] + tp[(size_t)t * DM + d];
  res[i] = 0.f;
}

// ---------------- residual add + RMSNorm ----------------
__global__ void rmsres_k(float* __restrict__ res, const float* __restrict__ hid,
                         const float* __restrict__ w, float* __restrict__ hn) {
  int r = blockIdx.x, d = threadIdx.x;
  size_t i = (size_t)r * DM + d;
  float s = res[i] + hid[i];
  res[i] = s;
  float sq = s * s;
  #pragma unroll
  for (int o = 1; o < 64; o <<= 1) sq += __shfl_xor(sq, o);
  __shared__ float part[8];
  __shared__ float scale;
  if ((d & 63) == 0) part[d >> 6] = sq;
  __syncthreads();
  if (d == 0) {
    float v = part[0] + part[1] + part[2] + part[3] + part[4] + part[5];
    scale = rsqrtf(v / (float)DM + 1e-5f);
  }
  __syncthreads();
  hn[i] = s * scale * w[d];
}

__global__ void final_k(const float* __restrict__ hid, const float* __restrict__ res,
                        const float* __restrict__ w, float* __restrict__ out) {
  int r = blockIdx.x, d = threadIdx.x;
  size_t i = (size_t)r * DM + d;
  float s = res[i] + hid[i];
  float sq = s * s;
  #pragma unroll
  for (int o = 1; o < 64; o <<= 1) sq += __shfl_xor(sq, o);
  __shared__ float part[8];
  __shared__ float scale;
  if ((d & 63) == 0) part[d >> 6] = sq;
  __syncthreads();
  if (d == 0) {
    float v = part[0] + part[1] + part[2] + part[3] + part[4] + part[5];
    scale = rsqrtf(v / (float)DM + 1e-5f);
  }
  __syncthreads();
  out[i] = s * scale * w[d];
}

// ---------------- bf16 MFMA GEMM (f32 A): C[M,N] = A * W^T ----------------
// Tile 128x128, BK=32, 4 waves (2x2); LDS pre-packed in fragment order.
__global__ __launch_bounds__(256) void gemm_bf16_k(const float* __restrict__ A, int lda,
                                                   const float* __restrict__ W,
                                                   float* __restrict__ C, int N, int K) {
  __shared__ __align__(16) uint2 As_l[1024];   // 8 KiB
  __shared__ __align__(16) uint2 Bs_l[1024];   // 8 KiB
  const int tid = threadIdx.x;
  const int m0 = blockIdx.y * 128, n0 = blockIdx.x * 128;
  const int lane = tid & 63, wv = tid >> 6;
  const int wr = wv >> 1, wc = wv & 1;
  f32x4 acc[4][4];
  #pragma unroll
  for (int i = 0; i < 4; ++i)
    #pragma unroll
    for (int j = 0; j < 4; ++j) acc[i][j] = (f32x4)0.f;

  for (int kt = 0; kt < K; kt += 32) {
    __syncthreads();
    #pragma unroll
    for (int i = 0; i < 4; ++i) {
      int q = tid + i * 256;
      int half = q & 1, l16 = (q >> 1) & 15, kg = (q >> 5) & 3, mb = q >> 7;
      int row = mb * 16 + l16, col = kg * 8 + half * 4;
      float4 va = *(const float4*)(A + (size_t)(m0 + row) * lda + kt + col);
      As_l[q] = pack4(va);
      float4 vw = *(const float4*)(W + (size_t)(n0 + row) * K + kt + col);
      Bs_l[q] = pack4(vw);
    }
    __syncthreads();
    short8b a[4], b[4];
    #pragma unroll
    for (int i = 0; i < 4; ++i) a[i] = ((const short8b*)As_l)[(wr * 4 + i) * 64 + lane];
    #pragma unroll
    for (int j = 0; j < 4; ++j) b[j] = ((const short8b*)Bs_l)[(wc * 4 + j) * 64 + lane];
    #pragma unroll
    for (int i = 0; i < 4; ++i)
      #pragma unroll
      for (int j = 0; j < 4; ++j)
        acc[i][j] = __builtin_amdgcn_mfma_f32_16x16x32_bf16(a[i], b[j], acc[i][j], 0, 0, 0);
  }

  const int r4 = (lane >> 4) * 4, cc = lane & 15;
  #pragma unroll
  for (int i = 0; i < 4; ++i) {
    #pragma unroll
    for (int v = 0; v < 4; ++v) {
      int row = m0 + wr * 64 + i * 16 + r4 + v;
      float* cp = C + (size_t)row * N + n0 + wc * 64 + cc;
      #pragma unroll
      for (int j = 0; j < 4; ++j) cp[j * 16] = acc[i][j][v];
    }
  }
}

// ---------------- bf16 MFMA GEMM (two bf16 A buffers summed): C = (Y1+Y2) * W^T ----------------
__global__ __launch_bounds__(256) void gemm_yy_k(const ushort_t* __restrict__ Y1,
                                                 const ushort_t* __restrict__ Y2,
                                                 const float* __restrict__ W,
                                                 float* __restrict__ C, int N, int K) {
  __shared__ __align__(16) uint2 As_l[1024];
  __shared__ __align__(16) uint2 Bs_l[1024];
  const int tid = threadIdx.x;
  const int m0 = blockIdx.y * 128, n0 = blockIdx.x * 128;
  const int lane = tid & 63, wv = tid >> 6;
  const int wr = wv >> 1, wc = wv & 1;
  f32x4 acc[4][4];
  #pragma unroll
  for (int i = 0; i < 4; ++i)
    #pragma unroll
    for (int j = 0; j < 4; ++j) acc[i][j] = (f32x4)0.f;

  for (int kt = 0; kt < K; kt += 32) {
    __syncthreads();
    #pragma unroll
    for (int i = 0; i < 4; ++i) {
      int q = tid + i * 256;
      int half = q & 1, l16 = (q >> 1) & 15, kg = (q >> 5) & 3, mb = q >> 7;
      int row = mb * 16 + l16, col = kg * 8 + half * 4;
      size_t off = (size_t)(m0 + row) * K + kt + col;
      uint2 p = *(const uint2*)(Y1 + off);
      uint2 r2 = *(const uint2*)(Y2 + off);
      float4 s;
      s.x = lo16(p.x) + lo16(r2.x);
      s.y = hi16(p.x) + hi16(r2.x);
      s.z = lo16(p.y) + lo16(r2.y);
      s.w = hi16(p.y) + hi16(r2.y);
      As_l[q] = pack4(s);
      float4 vw = *(const float4*)(W + (size_t)(n0 + row) * K + kt + col);
      Bs_l[q] = pack4(vw);
    }
    __syncthreads();
    short8b a[4], b[4];
    #pragma unroll
    for (int i = 0; i < 4; ++i) a[i] = ((const short8b*)As_l)[(wr * 4 + i) * 64 + lane];
    #pragma unroll
    for (int j = 0; j < 4; ++j) b[j] = ((const short8b*)Bs_l)[(wc * 4 + j) * 64 + lane];
    #pragma unroll
    for (int i = 0; i < 4; ++i)
      #pragma unroll
      for (int j = 0; j < 4; ++j)
        acc[i][j] = __builtin_amdgcn_mfma_f32_16x16x32_bf16(a[i], b[j], acc[i][j], 0, 0, 0);
  }

  const int r4 = (lane >> 4) * 4, cc = lane & 15;
  #pragma unroll
  for (int i = 0; i < 4; ++i) {
    #pragma unroll
    for (int v = 0; v < 4; ++v) {
      int row = m0 + wr * 64 + i * 16 + r4 + v;
      float* cp = C + (size_t)row * N + n0 + wc * 64 + cc;
      #pragma unroll
      for (int j = 0; j < 4; ++j) cp[j * 16] = acc[i][j][v];
    }
  }
}

// ---------------- causal conv (both directions) + SiLU -> bf16 ----------------
__global__ void conv_k(const float* __restrict__ xz,
                       const float* __restrict__ cw, const float* __restrict__ cb,
                       const float* __restrict__ cwb, const float* __restrict__ cbb,
                       ushort_t* __restrict__ xcf, ushort_t* __restrict__ xcb) {
  int r = blockIdx.x, dir = blockIdx.y;
  int b = r / L_SEQ, t = r % L_SEQ;
  const float* cwp = dir ? cwb : cw;
  const float* cbp = dir ? cbb : cb;
  ushort_t* outp = dir ? xcb : xcf;
  for (int d = threadIdx.x; d < DI; d += blockDim.x) {
    float acc = cbp[d];
    #pragma unroll
    for (int k = 0; k < 4; ++k) {
      int s = t - 3 + k;
      if (s >= 0) {
        int si = dir ? (L_SEQ - 1 - s) : s;
        acc += xz[((size_t)b * L_SEQ + si) * (2 * DI) + d] * cwp[d * 4 + k];
      }
    }
    outp[((size_t)b * L_SEQ + t) * DI + d] = f2bf(silu_f(acc));
  }
}

// ---------------- xproj stage 1 (MFMA, bf16 A): dbl = xc @ xw^T  [M=6272, N=56->64, K=768] ----------------
__global__ __launch_bounds__(256) void xproj1m_k(
    const ushort_t* __restrict__ xcf, const ushort_t* __restrict__ xcb,
    const float* __restrict__ xw, const float* __restrict__ xwb,
    float* __restrict__ dblR, float* __restrict__ BCf, float* __restrict__ BCb) {
  __shared__ __align__(16) uint2 As_l[512];    // 4 KiB
  __shared__ __align__(16) uint2 Bs_l[512];    // 4 KiB
  const int tid = threadIdx.x;
  const int m0 = blockIdx.x * 64;
  const int dir = blockIdx.y;
  const ushort_t* A = (dir ? xcb : xcf);
  const float* Wm = (dir ? xwb : xw);
  float* BCp = (dir ? BCb : BCf);
  const int lane = tid & 63, wv = tid >> 6;
  f32x4 acc[4];
  #pragma unroll
  for (int j = 0; j < 4; ++j) acc[j] = (f32x4)0.f;

  for (int kt = 0; kt < DI; kt += 32) {
    __syncthreads();
    #pragma unroll
    for (int i = 0; i < 2; ++i) {
      int q = tid + i * 256;
      int half = q & 1, l16 = (q >> 1) & 15, kg = (q >> 5) & 3, mb = q >> 7;
      int row = mb * 16 + l16, col = kg * 8 + half * 4;
      As_l[q] = *(const uint2*)(A + (size_t)(m0 + row) * DI + kt + col);  // 4 bf16 direct
      float4 vw = make_float4(0.f, 0.f, 0.f, 0.f);
      if (row < 56) vw = *(const float4*)(Wm + (size_t)row * DI + kt + col);
      Bs_l[q] = pack4(vw);
    }
    __syncthreads();
    short8b a = ((const short8b*)As_l)[wv * 64 + lane];
    #pragma unroll
    for (int j = 0; j < 4; ++j) {
      short8b b = ((const short8b*)Bs_l)[j * 64 + lane];
      acc[j] = __builtin_amdgcn_mfma_f32_16x16x32_bf16(a, b, acc[j], 0, 0, 0);
    }
  }

  const int r4 = (lane >> 4) * 4, cc = lane & 15;
  #pragma unroll
  for (int j = 0; j < 4; ++j) {
    int col = j * 16 + cc;
    #pragma unroll
    for (int v = 0; v < 4; ++v) {
      int row = m0 + wv * 16 + r4 + v;
      float val = acc[j][v];
      if (col < 24)       dblR[((size_t)dir * BLTOK + row) * 32 + col] = val;
      else if (col < 56)  BCp[(size_t)row * 32 + (col - 24)] = val;
    }
  }
}

// ---------------- xproj stage 2: dt = softplus(dblR[:, :24] @ dw^T + db) -> bf16 ----------------
__global__ __launch_bounds__(256) void xproj2_k(
    const float* __restrict__ dblR,
    const float* __restrict__ dw, const float* __restrict__ dwb,
    const float* __restrict__ db, const float* __restrict__ dbb,
    ushort_t* __restrict__ dtqf, ushort_t* __restrict__ dtqb) {
  __shared__ float sd[32][24];
  const int r0 = blockIdx.x * 32;
  const int dir = blockIdx.y;
  const int tid = threadIdx.x;
  const float* dwp = (dir ? dwb : dw);
  const float* dbp = (dir ? dbb : db);
  ushort_t* dtp = (dir ? dtqb : dtqf);
  #pragma unroll
  for (int i = 0; i < 3; ++i) {
    int idx = tid + i * 256;
    int r = idx / 24, j = idx - r * 24;
    sd[r][j] = dblR[((size_t)dir * BLTOK + r0 + r) * 32 + j];
  }
  __syncthreads();
  #pragma unroll
  for (int kk = 0; kk < 3; ++kk) {
    int d = kk * 256 + tid;
    float w[24];
    #pragma unroll
    for (int j = 0; j < 24; j += 4) {
      float4 wv = *(const float4*)&dwp[(size_t)d * DR + j];
      w[j] = wv.x; w[j + 1] = wv.y; w[j + 2] = wv.z; w[j + 3] = wv.w;
    }
    float bias = dbp[d];
    for (int r = 0; r < 32; ++r) {
      float acc = bias;
      #pragma unroll
      for (int j = 0; j < 24; ++j) acc += sd[r][j] * w[j];
      float dt = acc > 20.f ? acc : __logf(1.f + __expf(acc));
      dtp[(size_t)(r0 + r) * DI + d] = f2bf(dt);
    }
  }
}

// ---------------- scan pass A: per-chunk local state + decay product (bf16 I/O) ----------------
__global__ __launch_bounds__(256) void scanA_k(
    const ushort_t* __restrict__ dtqf, const ushort_t* __restrict__ dtqb,
    const ushort_t* __restrict__ xcf, const ushort_t* __restrict__ xcb,
    const float* __restrict__ BCf, const float* __restrict__ BCb,
    const float* __restrict__ Al, const float* __restrict__ Alb,
    ushort_t* __restrict__ Pbuf, ushort_t* __restrict__ Hloc) {
  int c = blockIdx.x, dir = blockIdx.y;
  int b = blockIdx.z / 3, ds = blockIdx.z % 3;
  int d = ds * 256 + threadIdx.x;
  const ushort_t* dtp = (dir ? dtqb : dtqf) + (size_t)b * L_SEQ * DI + d;
  const ushort_t* up  = (dir ? xcb : xcf) + (size_t)b * L_SEQ * DI + d;
  const float* bcp = (dir ? BCb : BCf) + (size_t)b * L_SEQ * 32;
  const float* alp = (dir ? Alb : Al) + (size_t)d * NS;
  float A[NS], h[NS], P[NS];
  #pragma unroll
  for (int n = 0; n < NS; ++n) { A[n] = -__expf(alp[n]); h[n] = 0.f; P[n] = 1.f; }
  int t0 = c * CHL;
  for (int t = t0; t < t0 + CHL; ++t) {
    float dt = bf2f(dtp[(size_t)t * DI]);
    float u  = bf2f(up[(size_t)t * DI]);
    float du = dt * u;
    const float* bc = bcp + (size_t)t * 32;
    #pragma unroll
    for (int n = 0; n < NS; ++n) {
      float a = __expf(dt * A[n]);
      h[n] = a * h[n] + du * bc[n];
      P[n] *= a;
    }
  }
  size_t base = ((((size_t)b * 2 + dir) * NCH + c) * DI + d) * NS;
  #pragma unroll
  for (int n = 0; n < NS; n += 4) {
    uint2 pv, hv;
    pv.x = (unsigned)f2bf(P[n])     | ((unsigned)f2bf(P[n + 1]) << 16);
    pv.y = (unsigned)f2bf(P[n + 2]) | ((unsigned)f2bf(P[n + 3]) << 16);
    hv.x = (unsigned)f2bf(h[n])     | ((unsigned)f2bf(h[n + 1]) << 16);
    hv.y = (unsigned)f2bf(h[n + 2]) | ((unsigned)f2bf(h[n + 3]) << 16);
    *(uint2*)&Pbuf[base + n] = pv;
    *(uint2*)&Hloc[base + n] = hv;
  }
}

// ---------------- scan pass B: one thread per (d,n); serial over NCH chunks (bf16, 2-deep prefetch) ----------------
__global__ __launch_bounds__(256) void scanBp_k(ushort_t* __restrict__ Pbuf,
                                                const ushort_t* __restrict__ Hloc) {
  const int dir = blockIdx.y, b = blockIdx.z;
  const int flat = blockIdx.x * 256 + threadIdx.x;           // d*NS + n
  const size_t stride = (size_t)DI * NS;                     // chunk stride
  size_t base = (size_t)(b * 2 + dir) * NCH * DI * NS + flat;
  float h = 0.f;
  ushort_t Pc0 = Pbuf[base], Hc0 = Hloc[base];
  ushort_t Pc1 = Pbuf[base + stride], Hc1 = Hloc[base + stride];
  for (int c = 0; c < NCH; ++c) {
    float P = bf2f(Pc0), H = bf2f(Hc0);
    Pc0 = Pc1; Hc0 = Hc1;
    size_t pre = base + 2 * stride;
    if (c + 2 < NCH) { Pc1 = Pbuf[pre]; Hc1 = Hloc[pre]; }
    Pbuf[base] = f2bf(h);              // store chunk-entry state
    h = P * h + H;
    base += stride;
  }
}

// ---------------- scan pass C: replay with entry state, emit gated output -> bf16 y buffers ----------------
__global__ __launch_bounds__(256) void scanC_k(
    const ushort_t* __restrict__ dtqf, const ushort_t* __restrict__ dtqb,
    const ushort_t* __restrict__ xcf, const ushort_t* __restrict__ xcb,
    const float* __restrict__ BCf, const float* __restrict__ BCb,
    const float* __restrict__ Al, const float* __restrict__ Alb,
    const float* __restrict__ Dd, const float* __restrict__ Ddb,
    const float* __restrict__ xz, const ushort_t* __restrict__ Hstart,
    ushort_t* __restrict__ ybf, ushort_t* __restrict__ ybb) {
  int c = blockIdx.x, dir = blockIdx.y;
  int b = blockIdx.z / 3, ds = blockIdx.z % 3;
  int d = ds * 256 + threadIdx.x;
  const ushort_t* dtp = (dir ? dtqb : dtqf) + (size_t)b * L_SEQ * DI + d;
  const ushort_t* up  = (dir ? xcb : xcf) + (size_t)b * L_SEQ * DI + d;
  const float* bcp = (dir ? BCb : BCf) + (size_t)b * L_SEQ * 32;
  const float* alp = (dir ? Alb : Al) + (size_t)d * NS;
  float Ddv = (dir ? Ddb : Dd)[d];
  ushort_t* yp = (dir ? ybb : ybf);
  float A[NS], h[NS];
  size_t base = ((((size_t)b * 2 + dir) * NCH + c) * DI + d) * NS;
  #pragma unroll
  for (int n = 0; n < NS; ++n) A[n] = -__expf(alp[n]);
  #pragma unroll
  for (int n = 0; n < NS; n += 2) {
    unsigned u2 = *(const unsigned*)&Hstart[base + n];
    h[n] = lo16(u2); h[n + 1] = hi16(u2);
  }
  int t0 = c * CHL;
  for (int t = t0; t < t0 + CHL; ++t) {
    float dt = bf2f(dtp[(size_t)t * DI]);
    float u  = bf2f(up[(size_t)t * DI]);
    float du = dt * u;
    const float* bc = bcp + (size_t)t * 32;
    float y = 0.f;
    #pragma unroll
    for (int n = 0; n < NS; ++n) {
      float a = __expf(dt * A[n]);
      h[n] = a * h[n] + du * bc[n];
      y += h[n] * bc[16 + n];
    }
    y += u * Ddv;
    int tw = dir ? (L_SEQ - 1 - t) : t;            // un-reverse bwd
    size_t row = (size_t)b * L_SEQ + tw;
    float z = xz[row * (2 * DI) + DI + d];
    yp[row * DI + d] = f2bf(y * silu_f(z));
  }
}

extern "C" void kernel_launch(void* const* d_in, const int* in_sizes, int n_in,
                              void* d_out, int out_size, void* d_ws, size_t ws_size,
                              hipStream_t stream) {
  const float* x        = (const float*)d_in[0];
  // d_in[1] = sgn_lengths (unused)
  const float* patch_w  = (const float*)d_in[2];
  const float* patch_b  = (const float*)d_in[3];
  const float* pos_emb  = (const float*)d_in[4];
  const float* temp_pos = (const float*)d_in[5];
  const float* in_proj_w= (const float*)d_in[6];
  const float* conv_w   = (const float*)d_in[7];
  const float* conv_b   = (const float*)d_in[8];
  const float* conv_w_b = (const float*)d_in[9];
  const float* conv_b_b = (const float*)d_in[10];
  const float* xproj_w  = (const float*)d_in[11];
  const float* xproj_w_b= (const float*)d_in[12];
  const float* dt_w     = (const float*)d_in[13];
  const float* dt_bias  = (const float*)d_in[14];
  const float* dt_w_b   = (const float*)d_in[15];
  const float* dt_bias_b= (const float*)d_in[16];
  const float* A_log    = (const float*)d_in[17];
  const float* A_log_b  = (const float*)d_in[18];
  const float* Ds       = (const float*)d_in[19];
  const float* Ds_b     = (const float*)d_in[20];
  const float* out_pw   = (const float*)d_in[21];
  const float* norm_w   = (const float*)d_in[22];
  const float* norm_f   = (const float*)d_in[23];
  float* out = (float*)d_out;

  // workspace layout: f32 region then bf16 region (~151 MiB total)
  float* ws = (float*)d_ws;
  const size_t SZH = (size_t)BLTOK * DM;
  float* hid = ws;
  float* res = hid + SZH;
  float* hn  = res + SZH;
  float* xz  = hn + SZH;                        // BLTOK * 1536 f32
  float* BCf = xz + (size_t)BLTOK * 2 * DI;     // BLTOK*32 f32
  float* BCb = BCf + (size_t)BLTOK * 32;
  float* dblR= BCb + (size_t)BLTOK * 32;        // [2][BLTOK][32] f32
  ushort_t* xcf  = (ushort_t*)(dblR + (size_t)2 * BLTOK * 32);
  ushort_t* xcb  = xcf + (size_t)BLTOK * DI;
  ushort_t* dtqf = xcb + (size_t)BLTOK * DI;
  ushort_t* dtqb = dtqf + (size_t)BLTOK * DI;
  ushort_t* ybf  = dtqb + (size_t)BLTOK * DI;
  ushort_t* ybb  = ybf + (size_t)BLTOK * DI;
  ushort_t* Pbuf = ybb + (size_t)BLTOK * DI;    // 2*2*NCH*DI*NS bf16
  ushort_t* Hlc  = Pbuf + (size_t)2 * 2 * NCH * DI * NS;

  // ---- patch embedding ----
  im2col_k<<<18816, 256, 0, stream>>>(x, xz);  // xz reused as im2col buffer
  gemm_bf16_k<<<dim3(3, 49), 256, 0, stream>>>(xz, DI, patch_w, hid, DM, DI);
  epi_k<<<BLTOK, DM, 0, stream>>>(hid, patch_b, pos_emb, temp_pos, res);

  // ---- 24 mamba layers ----
  for (int l = 0; l < 24; ++l) {
    rmsres_k<<<BLTOK, DM, 0, stream>>>(res, hid, norm_w + (size_t)l * DM, hn);
    gemm_bf16_k<<<dim3(12, 49), 256, 0, stream>>>(hn, DM,
        in_proj_w + (size_t)l * 2 * DI * DM, xz, 2 * DI, DM);
    conv_k<<<dim3(BLTOK, 2), 256, 0, stream>>>(xz,
        conv_w + (size_t)l * DI * 4, conv_b + (size_t)l * DI,
        conv_w_b + (size_t)l * DI * 4, conv_b_b + (size_t)l * DI, xcf, xcb);
    xproj1m_k<<<dim3(98, 2), 256, 0, stream>>>(xcf, xcb,
        xproj_w + (size_t)l * 56 * DI, xproj_w_b + (size_t)l * 56 * DI,
        dblR, BCf, BCb);
    xproj2_k<<<dim3(196, 2), 256, 0, stream>>>(dblR,
        dt_w + (size_t)l * DI * DR, dt_w_b + (size_t)l * DI * DR,
        dt_bias + (size_t)l * DI, dt_bias_b + (size_t)l * DI,
        dtqf, dtqb);
    scanA_k<<<dim3(NCH, 2, BATCH * 3), 256, 0, stream>>>(dtqf, dtqb, xcf, xcb, BCf, BCb,
        A_log + (size_t)l * DI * NS, A_log_b + (size_t)l * DI * NS, Pbuf, Hlc);
    scanBp_k<<<dim3(48, 2, BATCH), 256, 0, stream>>>(Pbuf, Hlc);
    scanC_k<<<dim3(NCH, 2, BATCH * 3), 256, 0, stream>>>(dtqf, dtqb, xcf, xcb, BCf, BCb,
        A_log + (size_t)l * DI * NS, A_log_b + (size_t)l * DI * NS,
        Ds + (size_t)l * DI, Ds_b + (size_t)l * DI, xz, Pbuf, ybf, ybb);
    gemm_yy_k<<<dim3(3, 49), 256, 0, stream>>>(ybf, ybb,
        out_pw + (size_t)l * DM * DI, hid, DM, DI);
  }

  // ---- final norm ----
  final_k<<<BLTOK, DM, 0, stream>>>(hid, res, norm_f, out);
}